// Round 2
// baseline (365.166 us; speedup 1.0000x reference)
//
#include <hip/hip_runtime.h>

#define TILE 64

// ---------------------------------------------------------------------------
// Kernel 1: HT[n*B + b] = pred_p[b*N + n] * p_scale[n] + p_mean[n] + elev[n]
// 64x64 LDS transpose tile; both global sides coalesced.
// ---------------------------------------------------------------------------
__global__ void k_build_ht(const float* __restrict__ pred_p,
                           const float* __restrict__ p_scale,
                           const float* __restrict__ p_mean,
                           const float* __restrict__ elev,
                           float* __restrict__ HT,
                           int B, int N) {
    __shared__ float tile[TILE][TILE + 1];
    const int n0 = blockIdx.x * TILE;
    const int b0 = blockIdx.y * TILE;
    const int tn = threadIdx.x % TILE;   // 0..63
    const int tw = threadIdx.x / TILE;   // 0..3

    const int n = n0 + tn;
    float sc = 0.f, mn = 0.f, el = 0.f;
    if (n < N) { sc = p_scale[n]; mn = p_mean[n]; el = elev[n]; }

    #pragma unroll
    for (int i = 0; i < TILE / 4; ++i) {
        const int bl = i * 4 + tw;
        float v = 0.f;
        if (n < N) v = pred_p[(size_t)(b0 + bl) * N + n] * sc + mn + el;
        tile[tn][bl] = v;
    }
    __syncthreads();
    #pragma unroll
    for (int i = 0; i < TILE / 4; ++i) {
        const int nl = i * 4 + tw;
        const int nn = n0 + nl;
        if (nn < N) HT[(size_t)nn * B + b0 + tn] = tile[nl][tn];
    }
}

// ---------------------------------------------------------------------------
// Kernel 2: per-edge fused work.
//   Q[b][e] = pred_f[b*E+e]*f_scale[e]+f_mean[e]   (staged in LDS, transposed)
//   mass scatter:  acc[dst*B+b] += Q ; acc[src*B+b] -= Q   (coalesced atomics)
//   head loss:     t = (HT[src*B+b] - HT[dst*B+b]) - R[e]*Q*|Q|^0.852
//                  sum t^2  -> block reduce -> atomicAdd(double)
// ---------------------------------------------------------------------------
__global__ void k_edges(const float* __restrict__ pred_f,
                        const float* __restrict__ f_scale,
                        const float* __restrict__ f_mean,
                        const float* __restrict__ Rcoef,
                        const int* __restrict__ esrc,
                        const int* __restrict__ edst,
                        const float* __restrict__ HT,
                        float* __restrict__ acc,
                        double* __restrict__ head_accum,
                        int B, int E) {
    __shared__ float qt[TILE][TILE + 1];   // [e_local][b_local]
    const int e0 = blockIdx.x * TILE;
    const int b0 = blockIdx.y * TILE;
    const int te = threadIdx.x % TILE;
    const int tw = threadIdx.x / TILE;

    const int e = e0 + te;
    const float fs = f_scale[e];
    const float fm = f_mean[e];
    #pragma unroll
    for (int i = 0; i < TILE / 4; ++i) {
        const int bl = i * 4 + tw;
        qt[te][bl] = pred_f[(size_t)(b0 + bl) * E + e] * fs + fm;
    }
    __syncthreads();

    double head = 0.0;
    const int bl = te;                 // lane -> batch (coalesced acc/HT)
    #pragma unroll
    for (int j = 0; j < TILE / 4; ++j) {
        const int el = tw * 16 + j;    // wave-uniform edge index
        const int ee = e0 + el;
        const int s = esrc[ee];
        const int d = edst[ee];
        const float q = qt[el][bl];

        atomicAdd(&acc[(size_t)d * B + b0 + bl],  q);
        atomicAdd(&acc[(size_t)s * B + b0 + bl], -q);

        const float hs = HT[(size_t)s * B + b0 + bl];
        const float hd = HT[(size_t)d * B + b0 + bl];
        const float fr = Rcoef[ee] * q * powf(fabsf(q), 0.852f);
        const float t = (hs - hd) - fr;
        head += (double)t * (double)t;
    }

    // block reduce (4 waves of 64)
    #pragma unroll
    for (int off = 32; off >= 1; off >>= 1)
        head += __shfl_down(head, off, 64);
    __shared__ double wsum[4];
    if ((threadIdx.x & 63) == 0) wsum[threadIdx.x >> 6] = head;
    __syncthreads();
    if (threadIdx.x == 0) {
        atomicAdd(head_accum, wsum[0] + wsum[1] + wsum[2] + wsum[3]);
    }
}

// ---------------------------------------------------------------------------
// Kernel 3: loss_mass partial sums.  q_net is acc[n*B+b]; d is
// true_d[b*N+n]*d_scale[n]+d_mean[n] staged through an LDS transpose tile.
// ---------------------------------------------------------------------------
__global__ void k_mass(const float* __restrict__ true_d,
                       const float* __restrict__ d_scale,
                       const float* __restrict__ d_mean,
                       const float* __restrict__ acc,
                       double* __restrict__ mass_accum,
                       int B, int N) {
    __shared__ float dt[TILE][TILE + 1];   // [n_local][b_local]
    const int n0 = blockIdx.x * TILE;
    const int b0 = blockIdx.y * TILE;
    const int tn = threadIdx.x % TILE;
    const int tw = threadIdx.x / TILE;

    const int n = n0 + tn;
    float sc = 0.f, mn = 0.f;
    if (n < N) { sc = d_scale[n]; mn = d_mean[n]; }
    #pragma unroll
    for (int i = 0; i < TILE / 4; ++i) {
        const int bl = i * 4 + tw;
        float v = 0.f;
        if (n < N) v = true_d[(size_t)(b0 + bl) * N + n] * sc + mn;
        dt[tn][bl] = v;
    }
    __syncthreads();

    double m = 0.0;
    const int bl = tn;
    #pragma unroll
    for (int j = 0; j < TILE / 4; ++j) {
        const int nl = tw * 16 + j;
        const int nn = n0 + nl;
        if (nn < N) {
            const float qn = acc[(size_t)nn * B + b0 + bl];
            const float t = qn - dt[nl][bl];
            m += (double)t * (double)t;
        }
    }
    #pragma unroll
    for (int off = 32; off >= 1; off >>= 1)
        m += __shfl_down(m, off, 64);
    __shared__ double wsum[4];
    if ((threadIdx.x & 63) == 0) wsum[threadIdx.x >> 6] = m;
    __syncthreads();
    if (threadIdx.x == 0) {
        atomicAdd(mass_accum, wsum[0] + wsum[1] + wsum[2] + wsum[3]);
    }
}

// ---------------------------------------------------------------------------
// Kernel 4: finalize scalars.
// ---------------------------------------------------------------------------
__global__ void k_final(const double* __restrict__ accum,
                        float* __restrict__ out,
                        double inv_mass_count, double inv_head_count) {
    out[0] = (float)(accum[0] * inv_mass_count);   // loss_mass
    out[1] = (float)(accum[1] * inv_head_count);   // loss_head
}

extern "C" void kernel_launch(void* const* d_in, const int* in_sizes, int n_in,
                              void* d_out, int out_size, void* d_ws, size_t ws_size,
                              hipStream_t stream) {
    const float* pred_p  = (const float*)d_in[0];
    const float* pred_f  = (const float*)d_in[1];
    const float* true_d  = (const float*)d_in[2];
    const float* p_mean  = (const float*)d_in[3];
    const float* p_scale = (const float*)d_in[4];
    const float* f_mean  = (const float*)d_in[5];
    const float* f_scale = (const float*)d_in[6];
    const float* d_mean  = (const float*)d_in[7];
    const float* d_scale = (const float*)d_in[8];
    const float* elev    = (const float*)d_in[9];
    const float* Rcoef   = (const float*)d_in[10];
    const int*   eidx    = (const int*)d_in[11];

    const int N = in_sizes[3];              // 50000
    const int E = in_sizes[10];             // 128000
    const int B = in_sizes[0] / N;          // 256

    const int* esrc = eidx;
    const int* edst = eidx + E;

    // workspace layout
    char* ws = (char*)d_ws;
    const size_t nb_bytes = (size_t)N * B * sizeof(float);       // 51.2 MB
    float*  HT    = (float*)ws;                                  // [N][B]
    float*  acc   = (float*)(ws + nb_bytes);                     // [N][B]
    double* accum = (double*)(ws + 2 * nb_bytes);                // [2]

    // zero acc + accumulators (HT is fully overwritten)
    hipMemsetAsync(acc, 0, nb_bytes + 2 * sizeof(double), stream);

    const int gn = (N + TILE - 1) / TILE;   // 782
    const int gb = B / TILE;                // 4
    const int ge = E / TILE;                // 2000

    k_build_ht<<<dim3(gn, gb), 256, 0, stream>>>(pred_p, p_scale, p_mean, elev,
                                                 HT, B, N);
    k_edges<<<dim3(ge, gb), 256, 0, stream>>>(pred_f, f_scale, f_mean, Rcoef,
                                              esrc, edst, HT, acc,
                                              accum + 1, B, E);
    k_mass<<<dim3(gn, gb), 256, 0, stream>>>(true_d, d_scale, d_mean, acc,
                                             accum + 0, B, N);
    k_final<<<1, 1, 0, stream>>>(accum, (float*)d_out,
                                 1.0 / ((double)B * (double)N),
                                 1.0 / ((double)B * (double)E));
}

// Round 3
// 343.018 us; speedup vs baseline: 1.0646x; 1.0646x over previous
//
#include <hip/hip_runtime.h>

#define TILE 64

// ---------------------------------------------------------------------------
// Kernel 1: HT[n*B + b] = pred_p[b*N + n] * p_scale[n] + p_mean[n] + elev[n]
// 64x64 LDS transpose tile; both global sides coalesced.
// ---------------------------------------------------------------------------
__global__ void k_build_ht(const float* __restrict__ pred_p,
                           const float* __restrict__ p_scale,
                           const float* __restrict__ p_mean,
                           const float* __restrict__ elev,
                           float* __restrict__ HT,
                           int B, int N) {
    __shared__ float tile[TILE][TILE + 1];
    const int n0 = blockIdx.x * TILE;
    const int b0 = blockIdx.y * TILE;
    const int tn = threadIdx.x % TILE;   // 0..63
    const int tw = threadIdx.x / TILE;   // 0..3

    const int n = n0 + tn;
    float sc = 0.f, mn = 0.f, el = 0.f;
    if (n < N) { sc = p_scale[n]; mn = p_mean[n]; el = elev[n]; }

    #pragma unroll
    for (int i = 0; i < TILE / 4; ++i) {
        const int bl = i * 4 + tw;
        float v = 0.f;
        if (n < N) v = pred_p[(size_t)(b0 + bl) * N + n] * sc + mn + el;
        tile[tn][bl] = v;
    }
    __syncthreads();
    #pragma unroll
    for (int i = 0; i < TILE / 4; ++i) {
        const int nl = i * 4 + tw;
        const int nn = n0 + nl;
        if (nn < N) HT[(size_t)nn * B + b0 + tn] = tile[nl][tn];
    }
}

// ---------------------------------------------------------------------------
// Kernel 2: per-edge fused work.
//   Q[b][e] = pred_f[b*E+e]*f_scale[e]+f_mean[e]   (staged in LDS, transposed)
//   head loss:     t = (HT[src*B+b] - HT[dst*B+b]) - R[e]*Q*|Q|^0.852
//                  sum t^2  -> block reduce -> atomicAdd(double)
//   mass scatter:  acc[dst*B+b] += Q ; acc[src*B+b] -= Q   (coalesced atomics)
// |q|^0.852 via v_log_f32/v_exp_f32 (exp2/log2), NOT libm powf.
// ---------------------------------------------------------------------------
__global__ void k_edges(const float* __restrict__ pred_f,
                        const float* __restrict__ f_scale,
                        const float* __restrict__ f_mean,
                        const float* __restrict__ Rcoef,
                        const int* __restrict__ esrc,
                        const int* __restrict__ edst,
                        const float* __restrict__ HT,
                        float* __restrict__ acc,
                        double* __restrict__ head_accum,
                        int B, int E) {
    __shared__ float qt[TILE][TILE + 1];   // [e_local][b_local]
    const int e0 = blockIdx.x * TILE;
    const int b0 = blockIdx.y * TILE;
    const int te = threadIdx.x % TILE;
    const int tw = threadIdx.x / TILE;

    const int e = e0 + te;
    const float fs = f_scale[e];
    const float fm = f_mean[e];
    #pragma unroll
    for (int i = 0; i < TILE / 4; ++i) {
        const int bl = i * 4 + tw;
        qt[te][bl] = pred_f[(size_t)(b0 + bl) * E + e] * fs + fm;
    }
    __syncthreads();

    double head = 0.0;
    const int bl = te;                 // lane -> batch (coalesced acc/HT)
    const float* HTb = HT + b0 + bl;
    float* accb = acc + b0 + bl;

    #pragma unroll
    for (int j = 0; j < TILE / 4; ++j) {
        const int el = tw * 16 + j;    // wave-uniform edge index
        const int ee = e0 + el;
        const int s = esrc[ee];
        const int d = edst[ee];
        const float q = qt[el][bl];

        // issue both gathers first; atomics (no result needed) go last so the
        // dependent-latency chain of this and following iterations overlaps.
        const float hs = HTb[(size_t)s * B];
        const float hd = HTb[(size_t)d * B];

        // |q|^0.852 = exp2(0.852*log2(|q|));  log2(0)=-inf -> exp2(-inf)=0  OK
        const float aq = fabsf(q);
        const float pw = exp2f(0.852f * __log2f(aq));
        const float fr = Rcoef[ee] * q * pw;
        const float t = (hs - hd) - fr;
        head += (double)t * (double)t;

        atomicAdd(&accb[(size_t)d * B],  q);
        atomicAdd(&accb[(size_t)s * B], -q);
    }

    // block reduce (4 waves of 64)
    #pragma unroll
    for (int off = 32; off >= 1; off >>= 1)
        head += __shfl_down(head, off, 64);
    __shared__ double wsum[4];
    if ((threadIdx.x & 63) == 0) wsum[threadIdx.x >> 6] = head;
    __syncthreads();
    if (threadIdx.x == 0) {
        atomicAdd(head_accum, wsum[0] + wsum[1] + wsum[2] + wsum[3]);
    }
}

// ---------------------------------------------------------------------------
// Kernel 3: loss_mass partial sums.  q_net is acc[n*B+b]; d is
// true_d[b*N+n]*d_scale[n]+d_mean[n] staged through an LDS transpose tile.
// ---------------------------------------------------------------------------
__global__ void k_mass(const float* __restrict__ true_d,
                       const float* __restrict__ d_scale,
                       const float* __restrict__ d_mean,
                       const float* __restrict__ acc,
                       double* __restrict__ mass_accum,
                       int B, int N) {
    __shared__ float dt[TILE][TILE + 1];   // [n_local][b_local]
    const int n0 = blockIdx.x * TILE;
    const int b0 = blockIdx.y * TILE;
    const int tn = threadIdx.x % TILE;
    const int tw = threadIdx.x / TILE;

    const int n = n0 + tn;
    float sc = 0.f, mn = 0.f;
    if (n < N) { sc = d_scale[n]; mn = d_mean[n]; }
    #pragma unroll
    for (int i = 0; i < TILE / 4; ++i) {
        const int bl = i * 4 + tw;
        float v = 0.f;
        if (n < N) v = true_d[(size_t)(b0 + bl) * N + n] * sc + mn;
        dt[tn][bl] = v;
    }
    __syncthreads();

    double m = 0.0;
    const int bl = tn;
    #pragma unroll
    for (int j = 0; j < TILE / 4; ++j) {
        const int nl = tw * 16 + j;
        const int nn = n0 + nl;
        if (nn < N) {
            const float qn = acc[(size_t)nn * B + b0 + bl];
            const float t = qn - dt[nl][bl];
            m += (double)t * (double)t;
        }
    }
    #pragma unroll
    for (int off = 32; off >= 1; off >>= 1)
        m += __shfl_down(m, off, 64);
    __shared__ double wsum[4];
    if ((threadIdx.x & 63) == 0) wsum[threadIdx.x >> 6] = m;
    __syncthreads();
    if (threadIdx.x == 0) {
        atomicAdd(mass_accum, wsum[0] + wsum[1] + wsum[2] + wsum[3]);
    }
}

// ---------------------------------------------------------------------------
// Kernel 4: finalize scalars.
// ---------------------------------------------------------------------------
__global__ void k_final(const double* __restrict__ accum,
                        float* __restrict__ out,
                        double inv_mass_count, double inv_head_count) {
    out[0] = (float)(accum[0] * inv_mass_count);   // loss_mass
    out[1] = (float)(accum[1] * inv_head_count);   // loss_head
}

extern "C" void kernel_launch(void* const* d_in, const int* in_sizes, int n_in,
                              void* d_out, int out_size, void* d_ws, size_t ws_size,
                              hipStream_t stream) {
    const float* pred_p  = (const float*)d_in[0];
    const float* pred_f  = (const float*)d_in[1];
    const float* true_d  = (const float*)d_in[2];
    const float* p_mean  = (const float*)d_in[3];
    const float* p_scale = (const float*)d_in[4];
    const float* f_mean  = (const float*)d_in[5];
    const float* f_scale = (const float*)d_in[6];
    const float* d_mean  = (const float*)d_in[7];
    const float* d_scale = (const float*)d_in[8];
    const float* elev    = (const float*)d_in[9];
    const float* Rcoef   = (const float*)d_in[10];
    const int*   eidx    = (const int*)d_in[11];

    const int N = in_sizes[3];              // 50000
    const int E = in_sizes[10];             // 128000
    const int B = in_sizes[0] / N;          // 256

    const int* esrc = eidx;
    const int* edst = eidx + E;

    // workspace layout
    char* ws = (char*)d_ws;
    const size_t nb_bytes = (size_t)N * B * sizeof(float);       // 51.2 MB
    float*  HT    = (float*)ws;                                  // [N][B]
    float*  acc   = (float*)(ws + nb_bytes);                     // [N][B]
    double* accum = (double*)(ws + 2 * nb_bytes);                // [2]

    // zero acc + accumulators (HT is fully overwritten)
    hipMemsetAsync(acc, 0, nb_bytes + 2 * sizeof(double), stream);

    const int gn = (N + TILE - 1) / TILE;   // 782
    const int gb = B / TILE;                // 4
    const int ge = E / TILE;                // 2000

    k_build_ht<<<dim3(gn, gb), 256, 0, stream>>>(pred_p, p_scale, p_mean, elev,
                                                 HT, B, N);
    k_edges<<<dim3(ge, gb), 256, 0, stream>>>(pred_f, f_scale, f_mean, Rcoef,
                                              esrc, edst, HT, acc,
                                              accum + 1, B, E);
    k_mass<<<dim3(gn, gb), 256, 0, stream>>>(true_d, d_scale, d_mean, acc,
                                             accum + 0, B, N);
    k_final<<<1, 1, 0, stream>>>(accum, (float*)d_out,
                                 1.0 / ((double)B * (double)N),
                                 1.0 / ((double)B * (double)E));
}